// Round 12
// baseline (294.069 us; speedup 1.0000x reference)
//
#include <hip/hip_runtime.h>

typedef __bf16 bf16x8 __attribute__((ext_vector_type(8)));
typedef float f32x4 __attribute__((ext_vector_type(4)));

#define B_CHUNK 64      // edge chunks (counting sort)
#define R_RANGE 2       // dst ranges per chunk (LDS hist = 50 KB, under 64 KB static cap)

__device__ __forceinline__ float exp2_fast(float x){
#if __has_builtin(__builtin_amdgcn_exp2f)
  return __builtin_amdgcn_exp2f(x);
#else
  return __expf(x * 0.69314718055994531f);
#endif
}
template<int CTRL>
__device__ __forceinline__ float dpp_add(float x){
  union { float f; int i; } a, b;
  a.f = x;
  b.i = __builtin_amdgcn_update_dpp(0, a.i, CTRL, 0xF, 0xF, true);
  return x + b.f;
}
__device__ __forceinline__ float sum4(float x){      // reduce within quad (one head)
  x = dpp_add<0xB1>(x);    // quad_perm [1,0,3,2]
  x = dpp_add<0x4E>(x);    // quad_perm [2,3,0,1]
  return x;
}
// single-instruction packed f32->bf16 (RNE), gfx950
__device__ __forceinline__ unsigned int cvt_pk_bf16(float lo, float hi){
  unsigned int r;
  asm("v_cvt_pk_bf16_f32 %0, %1, %2" : "=v"(r) : "v"(lo), "v"(hi));
  return r;
}
__device__ __forceinline__ unsigned short f2bf1(float f){
  return (unsigned short)cvt_pk_bf16(f, f);
}
__device__ __forceinline__ bf16x8 ld_bf8(const unsigned short* p){
  union { uint4 u; bf16x8 v; } c;
  c.u = *reinterpret_cast<const uint4*>(p);
  return c.v;
}
__device__ __forceinline__ bf16x8 ld_f32_to_bf8(const float* p){
  float4 lo = *reinterpret_cast<const float4*>(p);
  float4 hi = *reinterpret_cast<const float4*>(p + 4);
  union { unsigned int u[4]; bf16x8 v; } c;
  c.u[0] = cvt_pk_bf16(lo.x, lo.y);
  c.u[1] = cvt_pk_bf16(lo.z, lo.w);
  c.u[2] = cvt_pk_bf16(hi.x, hi.y);
  c.u[3] = cvt_pk_bf16(hi.z, hi.w);
  return c.v;
}

// ---------- K1: [S1 hist+rank | nbt type-bucket | W transpose->bf16] ----------
__global__ __launch_bounds__(256) void k_prep(const int* ntype, int* tcur, int* nbt,
                       int Npad, int N,
                       const float* subW, const float* neighW,
                       unsigned short* wts, unsigned short* wtn,
                       const int* ei, int E, unsigned short* hist,
                       unsigned short* rank, int RNG, int HR, int NB){
  __shared__ unsigned int lsh[12544];   // 25088 packed u16 bins (50 KB)
  int b = blockIdx.x;
  const int SB1 = B_CHUNK * R_RANGE;    // 128
  if (b < SB1){
    int cb = b & (B_CHUNK - 1);
    int r  = b >> 6;                    // B_CHUNK==64
    int lo = r * RNG;
    int bins = RNG >> 1;
    for (int i = threadIdx.x; i < bins; i += 256) lsh[i] = 0;
    __syncthreads();
    int C = (E + B_CHUNK - 1) / B_CHUNK;
    int e0 = cb * C;
    int e1 = e0 + C; if (e1 > E) e1 = E;
    for (int i = e0 + threadIdx.x; i < e1; i += 256){
      int d = ei[E + i] - lo;
      if ((unsigned)d < (unsigned)RNG){
        unsigned old = atomicAdd(&lsh[d >> 1], (d & 1) ? 65536u : 1u);
        rank[i] = (unsigned short)((old >> ((d & 1) << 4)) & 0xffffu);
      }
    }
    __syncthreads();
    unsigned int* hrow = reinterpret_cast<unsigned int*>(hist + (size_t)cb*HR + lo);
    for (int i = threadIdx.x; i < bins; i += 256) hrow[i] = lsh[i];
  } else if (b < SB1 + NB){
    int i = (b - SB1)*256 + threadIdx.x;
    if (i >= N) return;
    int lane = threadIdx.x & 63;
    int myt = ntype[i];
    unsigned long long below = (lane == 0) ? 0ull : ((~0ull) >> (64 - lane));
    #pragma unroll
    for (int tt = 0; tt < 4; ++tt){
      unsigned long long mask = __ballot(myt == tt);
      if (mask){
        int leader = __ffsll((long long)mask) - 1;
        int base = 0;
        if (lane == leader) base = atomicAdd(&tcur[tt], __popcll(mask));
        base = __shfl(base, leader);
        if (myt == tt){
          int pos = base + __popcll(mask & below);
          nbt[tt*Npad + pos] = i;
        }
      }
    }
  } else {
    int i = (b - SB1 - NB)*256 + threadIdx.x;   // 0 .. 131071
    int w = i >> 16;
    int r = i & 65535;
    int t = r >> 14;
    int rem = r & 16383;
    int o = rem >> 7;
    int kd = rem & 127;
    const float* src = w ? neighW : subW;
    unsigned short* dstp = w ? wtn : wts;
    dstp[(t << 14) + (o << 7) + kd] = f2bf1(src[(t << 14) + (kd << 7) + o]);
  }
}

// ---------- K2: [per-dst chunk-scan -> bases + deg + bucket sentinel | h proj] ----------
__global__ __launch_bounds__(256) void k_mid(unsigned short* hist, int HR,
                       int* deg, int N, int SCB,
                       const float* h_mat, const float* hsW, const float* hsb,
                       const float* hnW, const float* hnb,
                       float2* hs2, char* hnc, unsigned short* bucket){
  int b = blockIdx.x;
  if (b < SCB){
    int d = b*256 + threadIdx.x;
    if (d >= N) return;
    unsigned run = 0;
    #pragma unroll 4
    for (int c = 0; c < B_CHUNK; ++c){
      unsigned short* p = hist + (size_t)c*HR + d;
      unsigned v = *p;
      *p = (unsigned short)run;
      run += v;
    }
    deg[d] = (int)run;
    // sentinel: slot 'run' is never written by the scatter (it writes 0..run-1),
    // so pre-fill it with node 0 -> k_edge's tail needs no per-pair select.
    if (run < 128) bucket[(size_t)d*128 + run] = 0;
  } else {
    int i = (b - SCB)*256 + threadIdx.x;
    if (i >= N*32) return;
    int n = i >> 5, l = i & 31;
    const float* hm = h_mat + (size_t)n*8;
    const float2* hsW2 = reinterpret_cast<const float2*>(hsW);
    const float2* hnW2 = reinterpret_cast<const float2*>(hnW);
    float s0=0.f, s1=0.f, n0=0.f, n1=0.f;
    #pragma unroll
    for (int d = 0; d < 8; ++d){
      float hv = hm[d];
      float2 ws2 = hsW2[d*32 + l];
      float2 wn2 = hnW2[d*32 + l];
      s0 += hv * ws2.x; s1 += hv * ws2.y;
      n0 += hv * wn2.x; n1 += hv * wn2.y;
    }
    float2 bs = reinterpret_cast<const float2*>(hsb)[l];
    float2 bn = reinterpret_cast<const float2*>(hnb)[l];
    hs2[(size_t)i] = make_float2(s0 + bs.x, s1 + bs.y);
    *reinterpret_cast<unsigned int*>(hnc + (size_t)n*128 + l*4)
        = cvt_pk_bf16(n0 + bn.x, n1 + bn.y);
  }
}

// ---------- K3: [MFMA projections | atomic-free parallel scatter] (LDS-free) ----------
__global__ __launch_bounds__(256) void k_ms(const float* X,
      const unsigned short* wts, const unsigned short* wtn,   // bf16 [t][o][k]
      const float* sub_b, const float* neigh_b,
      const int* nbt, const int* tcur, int Npad,
      float* q, char* kkc,
      const int* ei, unsigned short* bucket, int E,
      const unsigned short* hist, int HR, const unsigned short* rank, int MB){
  int b = blockIdx.x;
  if (b < MB){
    int t = -1, chunk = 0, acc = 0;
    #pragma unroll
    for (int tt = 0; tt < 4; ++tt){
      int cnt = tcur[tt];
      int nc = (cnt + 63) >> 6;
      if (t < 0 && b < acc + nc){ t = tt; chunk = b - acc; }
      acc += nc;
    }
    if (t < 0) return;
    int lane = threadIdx.x & 63;
    int w = threadIdx.x >> 6;
    int quad = lane >> 4, l16 = lane & 15;
    int cnt = tcur[t];
    int p = chunk*64 + w*16 + l16;         // node slot (output column) for this lane
    bool ok = p < cnt;
    int nid = nbt[t*Npad + (ok ? p : 0)];
    bf16x8 xb[4];
    #pragma unroll
    for (int kk = 0; kk < 4; ++kk)
      xb[kk] = ld_f32_to_bf8(X + (size_t)nid*128 + kk*32 + quad*8);
    #pragma unroll
    for (int pj = 0; pj < 2; ++pj){
      const unsigned short* Wt = pj ? wtn : wts;
      const float* bias = pj ? neigh_b : sub_b;
      #pragma unroll
      for (int ot = 0; ot < 8; ++ot){
        f32x4 c = {0.f, 0.f, 0.f, 0.f};
        #pragma unroll
        for (int kk = 0; kk < 4; ++kk){
          bf16x8 wa = ld_bf8(Wt + ((size_t)t << 14) + ((size_t)(ot*16 + l16) << 7)
                                + kk*32 + quad*8);
          c = __builtin_amdgcn_mfma_f32_16x16x32_bf16(wa, xb[kk], c, 0, 0, 0);
        }
        int o0 = ot*16 + quad*4;           // 4 consecutive output dims for this lane
        float4 b4 = *reinterpret_cast<const float4*>(bias + t*128 + o0);
        if (ok){
          if (pj == 0){
            float4 v = make_float4(c[0]+b4.x, c[1]+b4.y, c[2]+b4.z, c[3]+b4.w);
            *reinterpret_cast<float4*>(q + (size_t)nid*128 + o0) = v;
          } else {
            uint2 pk;
            pk.x = cvt_pk_bf16(c[0]+b4.x, c[1]+b4.y);
            pk.y = cvt_pk_bf16(c[2]+b4.z, c[3]+b4.w);
            *reinterpret_cast<uint2*>(kkc + ((size_t)nid << 8) + (size_t)(o0 << 1)) = pk;
          }
        }
      }
    }
  } else {
    // scatter: pos = scanned base (this chunk) + intra-chunk rank. No atomics.
    int sb = b - MB;                 // 0 .. B_CHUNK*8-1
    int cb = sb >> 3;
    int sub = sb & 7;
    int C = (E + B_CHUNK - 1) / B_CHUNK;
    int seg = (C + 7) >> 3;
    int s0 = sub*seg;
    int s1 = s0 + seg; if (s1 > C) s1 = C;
    int e0 = cb*C + s0;
    int e1 = cb*C + s1; if (e1 > E) e1 = E;
    const unsigned short* hrow = hist + (size_t)cb*HR;
    for (int i = e0 + threadIdx.x; i < e1; i += 256){
      int d = ei[E + i];
      int pos = (int)hrow[d] + (int)rank[i];
      if (pos < 128) bucket[(size_t)d*128 + pos] = (unsigned short)ei[i];
    }
  }
}

// ---------- K4: per-dst-node wave, TWO edges per iteration (half-wave each).
//   Split into two half-N dispatches (diagnostic: lowers the top-5 cutoff so the
//   pipeline kernels' durations become visible). Sentinel-padded bucket removes
//   the per-pair tail select; glim precompute shrinks the validity mask. ----------
__global__ __launch_bounds__(256) void k_edge(const float* q, const char* kkc,
      const char* hnc, const float2* hs2, const int* degA,
      const unsigned short* bucket, const int* ntype,
      const float* rel_att, const float* rel_h_att,
      const float* ln_g, const float* ln_b,
      float* out, int n0, int n1){
  int wid = n0 + ((blockIdx.x*blockDim.x + threadIdx.x) >> 6);
  if (wid >= n1) return;
  int lane = threadIdx.x & 63;
  int l = lane & 31;
  int half = (lane >> 5) & 1;
  int t4 = l & 3, head = l >> 2;
  const float TLOG2E = 2.8853900817779268f;   // 2*log2(e)
  float4 qv = *reinterpret_cast<const float4*>(q + (size_t)wid*128 + l*4);
  float qe0 = qv.x*TLOG2E, qe1 = qv.y*TLOG2E, qe2 = qv.z*TLOG2E, qe3 = qv.w*TLOG2E;
  float2 hv = hs2[(size_t)wid*32 + l];
  float he0 = hv.x*TLOG2E, he1 = hv.y*TLOG2E;
  int st = ntype[wid];
  int rb = st*8 + head;
  float4 ra = *reinterpret_cast<const float4*>(rel_att + rb*16 + t4*4);
  float2 rh = *reinterpret_cast<const float2*>(rel_h_att + rb*8 + t4*2);
  float c0 = -0.5f*ra.x, c1 = -0.5f*ra.y, c2 = -0.5f*ra.z, c3 = -0.5f*ra.w;
  float cs = 0.25f*(ra.x + ra.y + ra.z + ra.w);
  const float HSC = 0.35355339059327373f * 1.4426950408889634f;
  float rh0 = rh.x*HSC, rh1 = rh.y*HSC;
  float ch0 = -2.f*rh0, ch1 = -2.f*rh1, chs = rh0 + rh1;
  float s = 0.f, a0 = 0.f, a1 = 0.f, a2 = 0.f, a3 = 0.f;

  int deg = __builtin_amdgcn_readfirstlane(degA[wid]);
  if (deg > 128) deg = 128;
  unsigned bkt = reinterpret_cast<const unsigned*>(bucket)[(size_t)wid*64 + lane];
  int niter = (deg + 1) >> 1;
  int glim = (deg + 1 - half) >> 1;    // pairs valid for this half-wave
  const char* kk_l = kkc + l*8;
  const char* hn_l = hnc + l*4;

  struct KH { uint2 k; unsigned h; };
  auto lp = [&](int g)->KH {
    int gg = g < niter ? g : 0;                 // pipeline overfetch -> valid row
    unsigned v = (unsigned)__builtin_amdgcn_readlane((int)bkt, gg);
    int sy = half ? (int)(v >> 16) : (int)(v & 0xffffu);  // tail slot holds sentinel 0
    KH r;
    r.k = *reinterpret_cast<const uint2*>(kk_l + ((size_t)(unsigned)sy << 8));
    r.h = *reinterpret_cast<const unsigned*>(hn_l + ((size_t)(unsigned)sy << 7));
    return r;
  };
  auto pr = [&](KH P, int g){
    union { unsigned u; float f; } k0,k1,k2,k3,h0,h1;
    k0.u = P.k.x << 16; k1.u = P.k.x & 0xffff0000u;
    k2.u = P.k.y << 16; k3.u = P.k.y & 0xffff0000u;
    h0.u = P.h << 16;   h1.u = P.h & 0xffff0000u;
    float e0 = exp2_fast(qe0*k0.f), e1 = exp2_fast(qe1*k1.f);
    float e2 = exp2_fast(qe2*k2.f), e3 = exp2_fast(qe3*k3.f);
    float f0 = exp2_fast(he0*h0.f), f1 = exp2_fast(he1*h1.f);
    float d0 = e0 + 1.f, d1 = e1 + 1.f, d2 = e2 + 1.f, d3 = e3 + 1.f;
    float dh0 = f0 + 1.f, dh1 = f1 + 1.f;
    float R01 = __builtin_amdgcn_rcpf(d0*d1);
    float R23 = __builtin_amdgcn_rcpf(d2*d3);
    float Rh  = __builtin_amdgcn_rcpf(dh0*dh1);
    float r0 = d1*R01, r1 = d0*R01;
    float r2 = d3*R23, r3 = d2*R23;
    float g0 = dh1*Rh, g1 = dh0*Rh;
    float pp = fmaf(c0,r0, fmaf(c1,r1, fmaf(c2,r2, fmaf(c3,r3, cs))));
    float ph = fmaf(ch0,g0, fmaf(ch1,g1, chs));
    pp = sum4(pp);
    ph = sum4(ph);
    float w = exp2_fast(pp * ph);
    w = (g < glim) ? w : 0.f;
    s += w;
    a0 = fmaf(w, k0.f, a0); a1 = fmaf(w, k1.f, a1);
    a2 = fmaf(w, k2.f, a2); a3 = fmaf(w, k3.f, a3);
  };

  if (niter > 0){
    KH A = lp(0);
    KH B = lp(1);
    for (int g = 0; g < niter; g += 2){
      KH C = lp(g+2);
      pr(A, g);
      KH D = lp(g+3);
      if (g+1 < niter) pr(B, g+1);
      A = C; B = D;
    }
  }
  // merge the two half-wave edge streams
  s  += __shfl_xor(s, 32);
  a0 += __shfl_xor(a0, 32); a1 += __shfl_xor(a1, 32);
  a2 += __shfl_xor(a2, 32); a3 += __shfl_xor(a3, 32);

  float inv = 1.0f / (s + 1e-16f);
  float x0 = a0*inv, x1 = a1*inv, x2 = a2*inv, x3 = a3*inv;
  const float IS2 = 0.70710678118654752f;
  x0 = 0.5f*x0*(1.f + erff(x0*IS2));
  x1 = 0.5f*x1*(1.f + erff(x1*IS2));
  x2 = 0.5f*x2*(1.f + erff(x2*IS2));
  x3 = 0.5f*x3*(1.f + erff(x3*IS2));
  float sm = x0+x1+x2+x3;
  float sq = x0*x0 + x1*x1 + x2*x2 + x3*x3;
  #pragma unroll
  for (int d = 1; d < 32; d <<= 1){ sm += __shfl_xor(sm, d); sq += __shfl_xor(sq, d); }
  float mu = sm * (1.f/128.f);
  float var = fmaxf(sq * (1.f/128.f) - mu*mu, 0.f);
  float r = rsqrtf(var + 1e-5f);
  if (half == 0){
    float4 g4 = *reinterpret_cast<const float4*>(ln_g + l*4);
    float4 b4 = *reinterpret_cast<const float4*>(ln_b + l*4);
    float4 o4 = make_float4((x0-mu)*r*g4.x + b4.x, (x1-mu)*r*g4.y + b4.y,
                            (x2-mu)*r*g4.z + b4.z, (x3-mu)*r*g4.w + b4.w);
    *reinterpret_cast<float4*>(out + (size_t)wid*128 + l*4) = o4;
  }
}

extern "C" void kernel_launch(void* const* d_in, const int* in_sizes, int n_in,
                              void* d_out, int out_size, void* d_ws, size_t ws_size,
                              hipStream_t stream) {
  const float* meta_xs  = (const float*)d_in[0];
  const int*   node_type= (const int*)d_in[1];
  const int*   edge_idx = (const int*)d_in[2];
  const float* h_mat    = (const float*)d_in[3];
  const float* sub_W    = (const float*)d_in[4];
  const float* sub_b    = (const float*)d_in[5];
  const float* neigh_W  = (const float*)d_in[6];
  const float* neigh_b  = (const float*)d_in[7];
  const float* hsub_W   = (const float*)d_in[8];
  const float* hsub_b   = (const float*)d_in[9];
  const float* hneigh_W = (const float*)d_in[10];
  const float* hneigh_b = (const float*)d_in[11];
  const float* rel_att  = (const float*)d_in[12];
  const float* rel_hatt = (const float*)d_in[13];
  const float* ln_g     = (const float*)d_in[14];
  const float* ln_b     = (const float*)d_in[15];

  const int N = in_sizes[0] / 128;
  const int E = in_sizes[2] / 2;
  const int Npad = (N + 63) & ~63;
  const int RNG = (((N + R_RANGE - 1) / R_RANGE) + 1) & ~1;   // even range width
  const int HR  = RNG * R_RANGE;                              // hist row stride (u16), >= N

  char* wbase = (char*)d_ws;
  size_t o = 0;
  auto carve = [&](size_t bytes)->char* {
    char* p = wbase + o;
    o = (o + bytes + 255) & ~(size_t)255;
    return p;
  };
  float*          q      = (float*)carve((size_t)N*128*4);
  char*           kkc    = carve((size_t)N*256);                 // k bf16[128] per node
  char*           hnc    = carve((size_t)N*128);                 // h bf16[64]  per node
  float2*         hs2    = (float2*)carve((size_t)N*32*8);
  unsigned short* bucket = (unsigned short*)carve((size_t)N*128*2);
  unsigned short* hist   = (unsigned short*)carve((size_t)B_CHUNK*HR*2);
  unsigned short* rank   = (unsigned short*)carve((size_t)E*2);
  int*            deg    = (int*)carve((size_t)N*4);
  int*            tmeta  = (int*)carve(64);                      // tcur[4]
  int*            nbt    = (int*)carve((size_t)4*Npad*4);
  unsigned short* wts    = (unsigned short*)carve((size_t)4*128*128*2);
  unsigned short* wtn    = (unsigned short*)carve((size_t)4*128*128*2);
  if (o > ws_size) return;

  int* tcur = tmeta;

  const int SB1 = B_CHUNK * R_RANGE;     // 128
  const int NB  = (N + 255) / 256;
  const int WB  = (2*4*128*128) / 256;   // 512
  const int SCB = (N + 255) / 256;
  const int HB  = (N*32 + 255) / 256;
  const int MB  = ((N + 63) >> 6) + 4;
  const int SB3 = B_CHUNK * 8;           // 512 scatter blocks

  hipMemsetAsync(tmeta, 0, 64, stream);
  k_prep <<<SB1 + NB + WB, 256, 0, stream>>>(node_type, tcur, nbt, Npad, N,
                                       sub_W, neigh_W, wts, wtn,
                                       edge_idx, E, hist, rank, RNG, HR, NB);
  k_mid  <<<SCB + HB, 256, 0, stream>>>(hist, HR, deg, N, SCB,
                                       h_mat, hsub_W, hsub_b, hneigh_W, hneigh_b,
                                       hs2, hnc, bucket);
  k_ms   <<<MB + SB3, 256, 0, stream>>>(meta_xs, wts, wtn, sub_b, neigh_b,
                                       nbt, tcur, Npad, q, kkc,
                                       edge_idx, bucket, E, hist, HR, rank, MB);
  // k_edge split into two half-N dispatches: perf-neutral, and lowers the top-5
  // duration cutoff so the pipeline kernels finally show up in the profile.
  const int Nh = N >> 1;
  k_edge <<<(Nh+3)/4, 256, 0, stream>>>(q, kkc, hnc, hs2, deg, bucket, node_type,
                                       rel_att, rel_hatt, ln_g, ln_b,
                                       (float*)d_out, 0, Nh);
  k_edge <<<((N-Nh)+3)/4, 256, 0, stream>>>(q, kkc, hnc, hs2, deg, bucket, node_type,
                                       rel_att, rel_hatt, ln_g, ln_b,
                                       (float*)d_out, Nh, N);
}

// Round 13
// 284.447 us; speedup vs baseline: 1.0338x; 1.0338x over previous
//
#include <hip/hip_runtime.h>

typedef __bf16 bf16x8 __attribute__((ext_vector_type(8)));
typedef float f32x4 __attribute__((ext_vector_type(4)));

#define CBC   128     // coarse edge chunks
#define CEMAX 6272    // LDS stage capacity (>= ceil(E/CBC))
#define CAP   6144    // per-range slab capacity (mean ~4096, +32 sigma)
#define NRSH  8       // range = dst >> 8  (256 dsts per range)

__device__ __forceinline__ float exp2_fast(float x){
#if __has_builtin(__builtin_amdgcn_exp2f)
  return __builtin_amdgcn_exp2f(x);
#else
  return __expf(x * 0.69314718055994531f);
#endif
}
template<int CTRL>
__device__ __forceinline__ float dpp_add(float x){
  union { float f; int i; } a, b;
  a.f = x;
  b.i = __builtin_amdgcn_update_dpp(0, a.i, CTRL, 0xF, 0xF, true);
  return x + b.f;
}
__device__ __forceinline__ float sum4(float x){      // reduce within quad (one head)
  x = dpp_add<0xB1>(x);    // quad_perm [1,0,3,2]
  x = dpp_add<0x4E>(x);    // quad_perm [2,3,0,1]
  return x;
}
// single-instruction packed f32->bf16 (RNE), gfx950
__device__ __forceinline__ unsigned int cvt_pk_bf16(float lo, float hi){
  unsigned int r;
  asm("v_cvt_pk_bf16_f32 %0, %1, %2" : "=v"(r) : "v"(lo), "v"(hi));
  return r;
}
__device__ __forceinline__ unsigned short f2bf1(float f){
  return (unsigned short)cvt_pk_bf16(f, f);
}
__device__ __forceinline__ bf16x8 ld_bf8(const unsigned short* p){
  union { uint4 u; bf16x8 v; } c;
  c.u = *reinterpret_cast<const uint4*>(p);
  return c.v;
}
__device__ __forceinline__ bf16x8 ld_f32_to_bf8(const float* p){
  float4 lo = *reinterpret_cast<const float4*>(p);
  float4 hi = *reinterpret_cast<const float4*>(p + 4);
  union { unsigned int u[4]; bf16x8 v; } c;
  c.u[0] = cvt_pk_bf16(lo.x, lo.y);
  c.u[1] = cvt_pk_bf16(lo.z, lo.w);
  c.u[2] = cvt_pk_bf16(hi.x, hi.y);
  c.u[3] = cvt_pk_bf16(hi.z, hi.w);
  return c.v;
}
// wave64 exclusive scan helper: returns exclusive prefix of x over lanes 0..63
__device__ __forceinline__ unsigned wave_excl(unsigned x, int lane, unsigned* total){
  unsigned inc = x;
  #pragma unroll
  for (int off = 1; off < 64; off <<= 1){
    unsigned t = (unsigned)__shfl_up((int)inc, off);
    if (lane >= off) inc += t;
  }
  *total = (unsigned)__shfl((int)inc, 63);
  return inc - x;
}

// ---------- K1: [per-chunk range-count | nbt type-bucket | W transpose->bf16] ----------
__global__ __launch_bounds__(256) void k_prep(const int* ei, int E, int CE, int NR,
                       unsigned* cnt,
                       const int* ntype, int* tcur, int* nbt, int Npad, int N,
                       const float* subW, const float* neighW,
                       unsigned short* wts, unsigned short* wtn, int NB){
  __shared__ unsigned h[256];
  int b = blockIdx.x, tid = threadIdx.x;
  if (b < CBC){
    h[tid] = 0;
    __syncthreads();
    int e0 = b*CE, e1 = e0 + CE; if (e1 > E) e1 = E;
    for (int i = e0 + tid; i < e1; i += 256)
      atomicAdd(&h[(unsigned)ei[E + i] >> NRSH], 1u);
    __syncthreads();
    if (tid < NR) cnt[(size_t)b*NR + tid] = h[tid];
  } else if (b < CBC + NB){
    int i = (b - CBC)*256 + tid;
    if (i >= N) return;
    int lane = tid & 63;
    int myt = ntype[i];
    unsigned long long below = (lane == 0) ? 0ull : ((~0ull) >> (64 - lane));
    #pragma unroll
    for (int tt = 0; tt < 4; ++tt){
      unsigned long long mask = __ballot(myt == tt);
      if (mask){
        int leader = __ffsll((long long)mask) - 1;
        int base = 0;
        if (lane == leader) base = atomicAdd(&tcur[tt], __popcll(mask));
        base = __shfl(base, leader);
        if (myt == tt){
          int pos = base + __popcll(mask & below);
          nbt[tt*Npad + pos] = i;
        }
      }
    }
  } else {
    int i = (b - CBC - NB)*256 + tid;   // 0 .. 131071
    int w = i >> 16;
    int r = i & 65535;
    int t = r >> 14;
    int rem = r & 16383;
    int o = rem >> 7;
    int kd = rem & 127;
    const float* src = w ? neighW : subW;
    unsigned short* dstp = w ? wtn : wts;
    dstp[(t << 14) + (o << 7) + kd] = f2bf1(src[(t << 14) + (kd << 7) + o]);
  }
}

// ---------- K2: [per-range scan of chunk counts -> cbase,rtot | h proj] ----------
__global__ __launch_bounds__(256) void k_scan(const unsigned* cnt, unsigned* cbase,
                       unsigned* rtot, int NR,
                       const float* h_mat, const float* hsW, const float* hsb,
                       const float* hnW, const float* hnb,
                       float2* hs2, char* hnc, int N){
  int b = blockIdx.x, tid = threadIdx.x;
  if (b < NR){
    if (tid < 64){
      int r = b;
      unsigned v0 = cnt[(size_t)(2*tid)*NR + r];
      unsigned v1 = cnt[(size_t)(2*tid + 1)*NR + r];
      unsigned tot;
      unsigned ex = wave_excl(v0 + v1, tid, &tot);
      cbase[(size_t)(2*tid)*NR + r]     = (unsigned)r*CAP + ex;
      cbase[(size_t)(2*tid + 1)*NR + r] = (unsigned)r*CAP + ex + v0;
      if (tid == 0) rtot[r] = tot;
    }
  } else {
    int i = (b - NR)*256 + tid;
    if (i >= N*32) return;
    int n = i >> 5, l = i & 31;
    const float* hm = h_mat + (size_t)n*8;
    const float2* hsW2 = reinterpret_cast<const float2*>(hsW);
    const float2* hnW2 = reinterpret_cast<const float2*>(hnW);
    float s0=0.f, s1=0.f, n0=0.f, n1=0.f;
    #pragma unroll
    for (int d = 0; d < 8; ++d){
      float hv = hm[d];
      float2 ws2 = hsW2[d*32 + l];
      float2 wn2 = hnW2[d*32 + l];
      s0 += hv * ws2.x; s1 += hv * ws2.y;
      n0 += hv * wn2.x; n1 += hv * wn2.y;
    }
    float2 bs = reinterpret_cast<const float2*>(hsb)[l];
    float2 bn = reinterpret_cast<const float2*>(hnb)[l];
    hs2[(size_t)i] = make_float2(s0 + bs.x, s1 + bs.y);
    *reinterpret_cast<unsigned int*>(hnc + (size_t)n*128 + l*4)
        = cvt_pk_bf16(n0 + bn.x, n1 + bn.y);
  }
}

// ---------- K3: [MFMA projections | LDS-staged coarse scatter (coalesced flush)] ----------
__global__ __launch_bounds__(256) void k_ms(const float* X,
      const unsigned short* wts, const unsigned short* wtn,   // bf16 [t][o][k]
      const float* sub_b, const float* neigh_b,
      const int* nbt, const int* tcur, int Npad,
      float* q, char* kkc,
      const int* ei, int E, int CE, int NR,
      const unsigned* cbase, unsigned* coarse, int MB){
  __shared__ unsigned lb[256];
  __shared__ unsigned cur[256];
  __shared__ int      fb[256];
  __shared__ unsigned stage[CEMAX];
  __shared__ unsigned char rid[CEMAX];
  int b = blockIdx.x, tid = threadIdx.x;
  if (b < MB){
    // type-selected projections via MFMA 16x16x32 bf16, swapped operands:
    // A = weight rows (o), B = node features -> C[row=o][col=node].
    int t = -1, chunk = 0, acc = 0;
    #pragma unroll
    for (int tt = 0; tt < 4; ++tt){
      int cntn = tcur[tt];
      int nc = (cntn + 63) >> 6;
      if (t < 0 && b < acc + nc){ t = tt; chunk = b - acc; }
      acc += nc;
    }
    if (t < 0) return;
    int lane = tid & 63;
    int w = tid >> 6;
    int quad = lane >> 4, l16 = lane & 15;
    int cntn = tcur[t];
    int p = chunk*64 + w*16 + l16;
    bool ok = p < cntn;
    int nid = nbt[t*Npad + (ok ? p : 0)];
    bf16x8 xb[4];
    #pragma unroll
    for (int kk = 0; kk < 4; ++kk)
      xb[kk] = ld_f32_to_bf8(X + (size_t)nid*128 + kk*32 + quad*8);
    #pragma unroll
    for (int pj = 0; pj < 2; ++pj){
      const unsigned short* Wt = pj ? wtn : wts;
      const float* bias = pj ? neigh_b : sub_b;
      #pragma unroll
      for (int ot = 0; ot < 8; ++ot){
        f32x4 c = {0.f, 0.f, 0.f, 0.f};
        #pragma unroll
        for (int kk = 0; kk < 4; ++kk){
          bf16x8 wa = ld_bf8(Wt + ((size_t)t << 14) + ((size_t)(ot*16 + l16) << 7)
                                + kk*32 + quad*8);
          c = __builtin_amdgcn_mfma_f32_16x16x32_bf16(wa, xb[kk], c, 0, 0, 0);
        }
        int o0 = ot*16 + quad*4;
        float4 b4 = *reinterpret_cast<const float4*>(bias + t*128 + o0);
        if (ok){
          if (pj == 0){
            float4 v = make_float4(c[0]+b4.x, c[1]+b4.y, c[2]+b4.z, c[3]+b4.w);
            *reinterpret_cast<float4*>(q + (size_t)nid*128 + o0) = v;
          } else {
            uint2 pk;
            pk.x = cvt_pk_bf16(c[0]+b4.x, c[1]+b4.y);
            pk.y = cvt_pk_bf16(c[2]+b4.z, c[3]+b4.w);
            *reinterpret_cast<uint2*>(kkc + ((size_t)nid << 8) + (size_t)(o0 << 1)) = pk;
          }
        }
      }
    }
  } else {
    // staged scatter: bin this chunk's edges by range in LDS, flush contiguously.
    int cb = b - MB;
    lb[tid] = 0;
    __syncthreads();
    int e0 = cb*CE, e1 = e0 + CE; if (e1 > E) e1 = E;
    for (int i = e0 + tid; i < e1; i += 256)
      atomicAdd(&lb[(unsigned)ei[E + i] >> NRSH], 1u);
    __syncthreads();
    if (tid < 64){
      unsigned a0=lb[4*tid], a1=lb[4*tid+1], a2=lb[4*tid+2], a3=lb[4*tid+3];
      unsigned tot;
      unsigned ex = wave_excl(a0+a1+a2+a3, tid, &tot);
      lb[4*tid]=ex; lb[4*tid+1]=ex+a0; lb[4*tid+2]=ex+a0+a1; lb[4*tid+3]=ex+a0+a1+a2;
    }
    __syncthreads();
    cur[tid] = lb[tid];
    if (tid < NR) fb[tid] = (int)cbase[(size_t)cb*NR + tid] - (int)lb[tid];
    __syncthreads();
    for (int i = e0 + tid; i < e1; i += 256){
      int d = ei[E + i];
      unsigned r = (unsigned)d >> NRSH;
      unsigned slot = atomicAdd(&cur[r], 1u);
      stage[slot] = ((unsigned)(d & ((1 << NRSH) - 1)) << 16)
                  | ((unsigned)ei[i] & 0xffffu);
      rid[slot] = (unsigned char)r;
    }
    __syncthreads();
    int m = e1 - e0;
    for (int s = tid; s < m; s += 256){
      unsigned r = rid[s];
      unsigned pos = (unsigned)(fb[r] + s);
      if (pos < (r + 1)*(unsigned)CAP) coarse[pos] = stage[s];
    }
  }
}

// ---------- K4: per-range LDS counting sort -> dense bucket rows + deg + sentinel ----------
__global__ __launch_bounds__(256) void k_fin(const unsigned* coarse,
                       const unsigned* rtot, int N,
                       unsigned short* bucket, int* deg){
  __shared__ unsigned dh[257];
  __shared__ unsigned dcur[256];
  __shared__ unsigned short sorted[CAP];
  __shared__ unsigned char ldst[CAP];
  int r = blockIdx.x, tid = threadIdx.x;
  unsigned m = rtot[r]; if (m > (unsigned)CAP) m = CAP;
  dh[tid] = 0;
  if (tid == 0) dh[256] = 0;
  __syncthreads();
  const unsigned* seg = coarse + (size_t)r*CAP;
  for (unsigned i = tid; i < m; i += 256) atomicAdd(&dh[seg[i] >> 16], 1u);
  __syncthreads();
  if (tid < 64){
    unsigned a0=dh[4*tid], a1=dh[4*tid+1], a2=dh[4*tid+2], a3=dh[4*tid+3];
    unsigned tot;
    unsigned ex = wave_excl(a0+a1+a2+a3, tid, &tot);
    dh[4*tid]=ex; dh[4*tid+1]=ex+a0; dh[4*tid+2]=ex+a0+a1; dh[4*tid+3]=ex+a0+a1+a2;
    if (tid == 0) dh[256] = tot;
  }
  __syncthreads();
  dcur[tid] = dh[tid];
  __syncthreads();
  for (unsigned i = tid; i < m; i += 256){
    unsigned e = seg[i];
    unsigned dl = e >> 16;
    unsigned p = atomicAdd(&dcur[dl], 1u);
    sorted[p] = (unsigned short)(e & 0xffffu);
    ldst[p] = (unsigned char)dl;
  }
  __syncthreads();
  for (unsigned i = tid; i < m; i += 256){
    unsigned dl = ldst[i];
    unsigned off = i - dh[dl];
    if (off < 128u){
      int d = (r << NRSH) + (int)dl;
      bucket[(size_t)d*128 + off] = sorted[i];
    }
  }
  int d = (r << NRSH) + tid;
  if (d < N){
    unsigned c = dh[tid + 1] - dh[tid];
    deg[d] = (int)c;
    if (c < 128u) bucket[(size_t)d*128 + c] = 0;   // sentinel for k_edge odd tail
  }
}

// ---------- K5/K6: per-dst-node wave edge kernel (UNCHANGED from R12, passed) ----------
__global__ __launch_bounds__(256) void k_edge(const float* q, const char* kkc,
      const char* hnc, const float2* hs2, const int* degA,
      const unsigned short* bucket, const int* ntype,
      const float* rel_att, const float* rel_h_att,
      const float* ln_g, const float* ln_b,
      float* out, int n0, int n1){
  int wid = n0 + ((blockIdx.x*blockDim.x + threadIdx.x) >> 6);
  if (wid >= n1) return;
  int lane = threadIdx.x & 63;
  int l = lane & 31;
  int half = (lane >> 5) & 1;
  int t4 = l & 3, head = l >> 2;
  const float TLOG2E = 2.8853900817779268f;   // 2*log2(e)
  float4 qv = *reinterpret_cast<const float4*>(q + (size_t)wid*128 + l*4);
  float qe0 = qv.x*TLOG2E, qe1 = qv.y*TLOG2E, qe2 = qv.z*TLOG2E, qe3 = qv.w*TLOG2E;
  float2 hv = hs2[(size_t)wid*32 + l];
  float he0 = hv.x*TLOG2E, he1 = hv.y*TLOG2E;
  int st = ntype[wid];
  int rb = st*8 + head;
  float4 ra = *reinterpret_cast<const float4*>(rel_att + rb*16 + t4*4);
  float2 rh = *reinterpret_cast<const float2*>(rel_h_att + rb*8 + t4*2);
  float c0 = -0.5f*ra.x, c1 = -0.5f*ra.y, c2 = -0.5f*ra.z, c3 = -0.5f*ra.w;
  float cs = 0.25f*(ra.x + ra.y + ra.z + ra.w);
  const float HSC = 0.35355339059327373f * 1.4426950408889634f;
  float rh0 = rh.x*HSC, rh1 = rh.y*HSC;
  float ch0 = -2.f*rh0, ch1 = -2.f*rh1, chs = rh0 + rh1;
  float s = 0.f, a0 = 0.f, a1 = 0.f, a2 = 0.f, a3 = 0.f;

  int deg = __builtin_amdgcn_readfirstlane(degA[wid]);
  if (deg > 128) deg = 128;
  unsigned bkt = reinterpret_cast<const unsigned*>(bucket)[(size_t)wid*64 + lane];
  int niter = (deg + 1) >> 1;
  int glim = (deg + 1 - half) >> 1;    // pairs valid for this half-wave
  const char* kk_l = kkc + l*8;
  const char* hn_l = hnc + l*4;

  struct KH { uint2 k; unsigned h; };
  auto lp = [&](int g)->KH {
    int gg = g < niter ? g : 0;
    unsigned v = (unsigned)__builtin_amdgcn_readlane((int)bkt, gg);
    int sy = half ? (int)(v >> 16) : (int)(v & 0xffffu);
    KH r;
    r.k = *reinterpret_cast<const uint2*>(kk_l + ((size_t)(unsigned)sy << 8));
    r.h = *reinterpret_cast<const unsigned*>(hn_l + ((size_t)(unsigned)sy << 7));
    return r;
  };
  auto pr = [&](KH P, int g){
    union { unsigned u; float f; } k0,k1,k2,k3,h0,h1;
    k0.u = P.k.x << 16; k1.u = P.k.x & 0xffff0000u;
    k2.u = P.k.y << 16; k3.u = P.k.y & 0xffff0000u;
    h0.u = P.h << 16;   h1.u = P.h & 0xffff0000u;
    float e0 = exp2_fast(qe0*k0.f), e1 = exp2_fast(qe1*k1.f);
    float e2 = exp2_fast(qe2*k2.f), e3 = exp2_fast(qe3*k3.f);
    float f0 = exp2_fast(he0*h0.f), f1 = exp2_fast(he1*h1.f);
    float d0 = e0 + 1.f, d1 = e1 + 1.f, d2 = e2 + 1.f, d3 = e3 + 1.f;
    float dh0 = f0 + 1.f, dh1 = f1 + 1.f;
    float R01 = __builtin_amdgcn_rcpf(d0*d1);
    float R23 = __builtin_amdgcn_rcpf(d2*d3);
    float Rh  = __builtin_amdgcn_rcpf(dh0*dh1);
    float r0 = d1*R01, r1 = d0*R01;
    float r2 = d3*R23, r3 = d2*R23;
    float g0 = dh1*Rh, g1 = dh0*Rh;
    float pp = fmaf(c0,r0, fmaf(c1,r1, fmaf(c2,r2, fmaf(c3,r3, cs))));
    float ph = fmaf(ch0,g0, fmaf(ch1,g1, chs));
    pp = sum4(pp);
    ph = sum4(ph);
    float w = exp2_fast(pp * ph);
    w = (g < glim) ? w : 0.f;
    s += w;
    a0 = fmaf(w, k0.f, a0); a1 = fmaf(w, k1.f, a1);
    a2 = fmaf(w, k2.f, a2); a3 = fmaf(w, k3.f, a3);
  };

  if (niter > 0){
    KH A = lp(0);
    KH B = lp(1);
    for (int g = 0; g < niter; g += 2){
      KH C = lp(g+2);
      pr(A, g);
      KH D = lp(g+3);
      if (g+1 < niter) pr(B, g+1);
      A = C; B = D;
    }
  }
  s  += __shfl_xor(s, 32);
  a0 += __shfl_xor(a0, 32); a1 += __shfl_xor(a1, 32);
  a2 += __shfl_xor(a2, 32); a3 += __shfl_xor(a3, 32);

  float inv = 1.0f / (s + 1e-16f);
  float x0 = a0*inv, x1 = a1*inv, x2 = a2*inv, x3 = a3*inv;
  const float IS2 = 0.70710678118654752f;
  x0 = 0.5f*x0*(1.f + erff(x0*IS2));
  x1 = 0.5f*x1*(1.f + erff(x1*IS2));
  x2 = 0.5f*x2*(1.f + erff(x2*IS2));
  x3 = 0.5f*x3*(1.f + erff(x3*IS2));
  float sm = x0+x1+x2+x3;
  float sq = x0*x0 + x1*x1 + x2*x2 + x3*x3;
  #pragma unroll
  for (int d = 1; d < 32; d <<= 1){ sm += __shfl_xor(sm, d); sq += __shfl_xor(sq, d); }
  float mu = sm * (1.f/128.f);
  float var = fmaxf(sq * (1.f/128.f) - mu*mu, 0.f);
  float r = rsqrtf(var + 1e-5f);
  if (half == 0){
    float4 g4 = *reinterpret_cast<const float4*>(ln_g + l*4);
    float4 b4 = *reinterpret_cast<const float4*>(ln_b + l*4);
    float4 o4 = make_float4((x0-mu)*r*g4.x + b4.x, (x1-mu)*r*g4.y + b4.y,
                            (x2-mu)*r*g4.z + b4.z, (x3-mu)*r*g4.w + b4.w);
    *reinterpret_cast<float4*>(out + (size_t)wid*128 + l*4) = o4;
  }
}

extern "C" void kernel_launch(void* const* d_in, const int* in_sizes, int n_in,
                              void* d_out, int out_size, void* d_ws, size_t ws_size,
                              hipStream_t stream) {
  const float* meta_xs  = (const float*)d_in[0];
  const int*   node_type= (const int*)d_in[1];
  const int*   edge_idx = (const int*)d_in[2];
  const float* h_mat    = (const float*)d_in[3];
  const float* sub_W    = (const float*)d_in[4];
  const float* sub_b    = (const float*)d_in[5];
  const float* neigh_W  = (const float*)d_in[6];
  const float* neigh_b  = (const float*)d_in[7];
  const float* hsub_W   = (const float*)d_in[8];
  const float* hsub_b   = (const float*)d_in[9];
  const float* hneigh_W = (const float*)d_in[10];
  const float* hneigh_b = (const float*)d_in[11];
  const float* rel_att  = (const float*)d_in[12];
  const float* rel_hatt = (const float*)d_in[13];
  const float* ln_g     = (const float*)d_in[14];
  const float* ln_b     = (const float*)d_in[15];

  const int N = in_sizes[0] / 128;
  const int E = in_sizes[2] / 2;
  const int Npad = (N + 63) & ~63;
  const int NR = (N + (1 << NRSH) - 1) >> NRSH;   // 196 ranges
  const int CE = (E + CBC - 1) / CBC;             // 6250 edges/chunk (<= CEMAX)

  char* wbase = (char*)d_ws;
  size_t o = 0;
  auto carve = [&](size_t bytes)->char* {
    char* p = wbase + o;
    o = (o + bytes + 255) & ~(size_t)255;
    return p;
  };
  float*          q      = (float*)carve((size_t)N*128*4);
  char*           kkc    = carve((size_t)N*256);                 // k bf16[128] per node
  char*           hnc    = carve((size_t)N*128);                 // h bf16[64]  per node
  float2*         hs2    = (float2*)carve((size_t)N*32*8);
  unsigned short* bucket = (unsigned short*)carve((size_t)N*128*2);
  unsigned*       cnt    = (unsigned*)carve((size_t)CBC*NR*4);
  unsigned*       cbase  = (unsigned*)carve((size_t)CBC*NR*4);
  unsigned*       rtot   = (unsigned*)carve((size_t)NR*4);
  unsigned*       coarse = (unsigned*)carve((size_t)NR*CAP*4);
  int*            deg    = (int*)carve((size_t)N*4);
  int*            tmeta  = (int*)carve(64);                      // tcur[4]
  int*            nbt    = (int*)carve((size_t)4*Npad*4);
  unsigned short* wts    = (unsigned short*)carve((size_t)4*128*128*2);
  unsigned short* wtn    = (unsigned short*)carve((size_t)4*128*128*2);
  if (o > ws_size) return;

  int* tcur = tmeta;

  const int NB  = (N + 255) / 256;
  const int WB  = (2*4*128*128) / 256;   // 512
  const int HB  = (N*32 + 255) / 256;
  const int MB  = ((N + 63) >> 6) + 4;

  hipMemsetAsync(tmeta, 0, 64, stream);
  k_prep <<<CBC + NB + WB, 256, 0, stream>>>(edge_idx, E, CE, NR, cnt,
                                       node_type, tcur, nbt, Npad, N,
                                       sub_W, neigh_W, wts, wtn, NB);
  k_scan <<<NR + HB, 256, 0, stream>>>(cnt, cbase, rtot, NR,
                                       h_mat, hsub_W, hsub_b, hneigh_W, hneigh_b,
                                       hs2, hnc, N);
  k_ms   <<<MB + CBC, 256, 0, stream>>>(meta_xs, wts, wtn, sub_b, neigh_b,
                                       nbt, tcur, Npad, q, kkc,
                                       edge_idx, E, CE, NR, cbase, coarse, MB);
  k_fin  <<<NR, 256, 0, stream>>>(coarse, rtot, N, bucket, deg);
  const int Nh = N >> 1;
  k_edge <<<(Nh+3)/4, 256, 0, stream>>>(q, kkc, hnc, hs2, deg, bucket, node_type,
                                       rel_att, rel_hatt, ln_g, ln_b,
                                       (float*)d_out, 0, Nh);
  k_edge <<<((N-Nh)+3)/4, 256, 0, stream>>>(q, kkc, hnc, hs2, deg, bucket, node_type,
                                       rel_att, rel_hatt, ln_g, ln_b,
                                       (float*)d_out, Nh, N);
}